// Round 1
// baseline (448.042 us; speedup 1.0000x reference)
//
#include <hip/hip_runtime.h>
#include <hip/hip_bf16.h>

typedef __attribute__((ext_vector_type(8))) short short8;
typedef __attribute__((ext_vector_type(4))) float f32x4;

#define O 144
#define NB 32
#define GT 256
#define NPAIRS 10440   // 144*145/2
#define NTILES 164     // ceil(10440/64)

// workspace byte offsets
#define WS_WT   0u          // 3 * 256*256 bf16 (transposed weights, Wt[e][k])
#define WS_U    393216u     // 32*144*256 bf16
#define WS_V    2752512u    // 32*144*256 bf16
#define WS_W    5111808u    // 32*256 f32
#define WS_REL  5144576u    // 32*256 f32

__device__ __forceinline__ float bf2f(unsigned short b){
  unsigned int uu = ((unsigned int)b) << 16;
  return __builtin_bit_cast(float, uu);
}
__device__ __forceinline__ unsigned short f2bf(float f){
  unsigned int uu = __builtin_bit_cast(unsigned int, f);
  unsigned int lsb = (uu >> 16) & 1u;
  uu += 0x7fffu + lsb;               // round-to-nearest-even
  return (unsigned short)(uu >> 16);
}

// ---- prep: u[n,o,:] = feats(n,o) . gW0[0:26,:],  v = feats . gW0[26:52,:] ----
__global__ void prep_uv(const float* __restrict__ x, const float* __restrict__ gW0,
                        unsigned short* __restrict__ u, unsigned short* __restrict__ v){
  int blk = blockIdx.x;
  int n = blk / O, o = blk % O;
  __shared__ float f[26];
  int t = threadIdx.x;
  if (t < 24) f[t] = x[(n*24 + t)*144 + o];
  if (t == 24) f[24] = -1.f + 2.f * (float)(o / 12) / 11.f;  // xc (row coord)
  if (t == 25) f[25] = -1.f + 2.f * (float)(o % 12) / 11.f;  // yc (col coord)
  __syncthreads();
  float su = 0.f, sv = 0.f;
  #pragma unroll
  for (int c = 0; c < 26; c++){
    float fc = f[c];
    su += fc * gW0[c*GT + t];
    sv += fc * gW0[(26 + c)*GT + t];
  }
  u[(n*O + o)*GT + t] = f2bf(su);
  v[(n*O + o)*GT + t] = f2bf(sv);
}

// ---- prep: w[n,:] = q[n] . gW0[52:180,:] + gb0 ; also zero rel ----
__global__ void prep_w(const float* __restrict__ q, const float* __restrict__ gW0,
                       const float* __restrict__ gb0, float* __restrict__ wv_,
                       float* __restrict__ rel){
  int n = blockIdx.x, t = threadIdx.x;
  __shared__ float ql[128];
  if (t < 128) ql[t] = q[n*128 + t];
  __syncthreads();
  float s = gb0[t];
  for (int d = 0; d < 128; d++) s += ql[d] * gW0[(52 + d)*GT + t];
  wv_[n*GT + t] = s;
  rel[n*GT + t] = 0.f;
}

// ---- prep: Wt_l[e][k] = W_l[k][e] as bf16 ----
__global__ void prep_wt(const float* __restrict__ gW1, const float* __restrict__ gW2,
                        const float* __restrict__ gW3, unsigned short* __restrict__ Wt){
  int li = blockIdx.x >> 8;
  int e  = blockIdx.x & 255;
  int k  = threadIdx.x;
  const float* W = (li == 0) ? gW1 : (li == 1) ? gW2 : gW3;
  Wt[li*65536 + e*GT + k] = f2bf(W[k*GT + e]);
}

// ---- main fused kernel: h0 build + 3 MFMA layers + masked column-sum ----
__global__ __launch_bounds__(256) void rn_main(
    const unsigned short* __restrict__ u, const unsigned short* __restrict__ v,
    const float* __restrict__ wv_, const unsigned short* __restrict__ Wt,
    const float* __restrict__ gb1, const float* __restrict__ gb2,
    const float* __restrict__ gb3, float* __restrict__ rel)
{
  __shared__ short8 hbuf[2048];          // 64 rows x 256 cols bf16, XOR-swizzled
  char* lds = (char*)hbuf;

  const int tid  = threadIdx.x;
  const int lane = tid & 63;
  const int wav  = tid >> 6;             // 0..3, owns cols [wav*64, wav*64+64)
  const int n    = blockIdx.x / NTILES;
  const int tile = blockIdx.x - n*NTILES;
  const int tbase = tile * 64;

  // ---- stage h0 = relu(u[n,b] + v[n,a] + w[n]), row r <-> pair tbase+r ----
  {
    int r  = tid >> 2;
    int pt = tbase + r;
    int valid = pt < NPAIRS;
    int pa = 0, pb = 0;
    if (valid){
      pa = (int)((sqrtf(8.f*(float)pt + 1.f) - 1.f) * 0.5f);
      while ((pa + 1)*(pa + 2)/2 <= pt) pa++;
      while (pa*(pa + 1)/2 > pt) pa--;
      pb = pt - pa*(pa + 1)/2;
    }
    const unsigned short* up = u + (size_t)(n*O + pb)*GT;
    const unsigned short* vp = v + (size_t)(n*O + pa)*GT;
    const float* wp = wv_ + n*GT;
    int c0 = (tid & 3) * 64;
    for (int cc = 0; cc < 64; cc += 8){
      int col = c0 + cc;
      short8 hv;
      if (valid){
        short8 uu = *(const short8*)(up + col);
        short8 vv = *(const short8*)(vp + col);
        #pragma unroll
        for (int j = 0; j < 8; j++){
          float s = bf2f((unsigned short)uu[j]) + bf2f((unsigned short)vv[j]) + wp[col + j];
          hv[j] = (short)f2bf(fmaxf(s, 0.f));
        }
      } else {
        #pragma unroll
        for (int j = 0; j < 8; j++) hv[j] = 0;
      }
      int addr = r*512 + (((col*2) ^ ((r & 7) << 4)));
      *(short8*)(lds + addr) = hv;
    }
  }
  __syncthreads();

  const int colbase = wav * 64;
  f32x4 acc[4][4];

  #pragma unroll
  for (int L = 0; L < 3; L++){
    const unsigned short* Wl = Wt + L*65536;
    const float* gb = (L == 0) ? gb1 : (L == 1) ? gb2 : gb3;

    #pragma unroll
    for (int m = 0; m < 4; m++)
      #pragma unroll
      for (int nn = 0; nn < 4; nn++)
        acc[m][nn] = (f32x4){0.f, 0.f, 0.f, 0.f};

    #pragma unroll
    for (int kk = 0; kk < 8; kk++){
      int kb = kk*64 + ((lane >> 4) << 4);   // byte offset of this lane's k-slice
      short8 af[4], bfr[4];
      #pragma unroll
      for (int m = 0; m < 4; m++){
        int row = (lane & 15) + m*16;
        af[m] = *(short8*)(lds + row*512 + (kb ^ ((row & 7) << 4)));
      }
      #pragma unroll
      for (int nn = 0; nn < 4; nn++){
        int col = colbase + nn*16 + (lane & 15);
        bfr[nn] = *(const short8*)((const char*)Wl + col*512 + kb);
      }
      #pragma unroll
      for (int m = 0; m < 4; m++)
        #pragma unroll
        for (int nn = 0; nn < 4; nn++)
          acc[m][nn] = __builtin_amdgcn_mfma_f32_16x16x32_bf16(af[m], bfr[nn], acc[m][nn], 0, 0, 0);
    }

    float bcol[4];
    #pragma unroll
    for (int nn = 0; nn < 4; nn++) bcol[nn] = gb[colbase + nn*16 + (lane & 15)];

    if (L < 2){
      __syncthreads();                     // all waves done reading h_in
      #pragma unroll
      for (int m = 0; m < 4; m++){
        #pragma unroll
        for (int nn = 0; nn < 4; nn++){
          int col = colbase + nn*16 + (lane & 15);
          #pragma unroll
          for (int j = 0; j < 4; j++){
            int row = m*16 + ((lane >> 4) << 2) + j;
            float hv = fmaxf(acc[m][nn][j] + bcol[nn], 0.f);
            *(unsigned short*)(lds + row*512 + (((col*2) ^ ((row & 7) << 4)))) = f2bf(hv);
          }
        }
      }
      __syncthreads();                     // h_out visible to all waves
    } else {
      // layer 3: bias+relu, mask tail rows, column sums -> atomic into rel
      #pragma unroll
      for (int nn = 0; nn < 4; nn++){
        float s = 0.f;
        #pragma unroll
        for (int m = 0; m < 4; m++){
          #pragma unroll
          for (int j = 0; j < 4; j++){
            int row = m*16 + ((lane >> 4) << 2) + j;
            float hv = fmaxf(acc[m][nn][j] + bcol[nn], 0.f);
            if (tbase + row < NPAIRS) s += hv;
          }
        }
        s += __shfl_xor(s, 16);
        s += __shfl_xor(s, 32);
        if (lane < 16) atomicAdd(&rel[n*GT + colbase + nn*16 + lane], s);
      }
    }
  }
}

// ---- f_phi: per-batch 256->256->256->28, f32 ----
__global__ void fphi(const float* __restrict__ rel,
                     const float* __restrict__ fW0, const float* __restrict__ fb0,
                     const float* __restrict__ fW1, const float* __restrict__ fb1,
                     const float* __restrict__ fW2, const float* __restrict__ fb2,
                     float* __restrict__ out){
  int n = blockIdx.x, t = threadIdx.x;
  __shared__ float h[256], y[256];
  h[t] = rel[n*GT + t];
  __syncthreads();
  float s = fb0[t];
  for (int k = 0; k < 256; k++) s += h[k] * fW0[k*GT + t];
  y[t] = fmaxf(s, 0.f);
  __syncthreads();
  s = fb1[t];
  for (int k = 0; k < 256; k++) s += y[k] * fW1[k*GT + t];
  __syncthreads();                 // everyone done reading y; safe to reuse h
  h[t] = fmaxf(s, 0.f);
  __syncthreads();
  if (t < 28){
    s = fb2[t];
    for (int k = 0; k < 256; k++) s += h[k] * fW2[k*28 + t];
    out[n*28 + t] = s;
  }
}

extern "C" void kernel_launch(void* const* d_in, const int* in_sizes, int n_in,
                              void* d_out, int out_size, void* d_ws, size_t ws_size,
                              hipStream_t stream){
  (void)in_sizes; (void)n_in; (void)out_size; (void)ws_size;
  const float* x   = (const float*)d_in[0];
  const float* q   = (const float*)d_in[1];
  const float* gW0 = (const float*)d_in[2];
  const float* gb0 = (const float*)d_in[3];
  const float* gW1 = (const float*)d_in[4];
  const float* gb1 = (const float*)d_in[5];
  const float* gW2 = (const float*)d_in[6];
  const float* gb2 = (const float*)d_in[7];
  const float* gW3 = (const float*)d_in[8];
  const float* gb3 = (const float*)d_in[9];
  const float* fW0 = (const float*)d_in[10];
  const float* fb0 = (const float*)d_in[11];
  const float* fW1 = (const float*)d_in[12];
  const float* fb1 = (const float*)d_in[13];
  const float* fW2 = (const float*)d_in[14];
  const float* fb2 = (const float*)d_in[15];

  char* ws = (char*)d_ws;
  unsigned short* Wt = (unsigned short*)(ws + WS_WT);
  unsigned short* u  = (unsigned short*)(ws + WS_U);
  unsigned short* v  = (unsigned short*)(ws + WS_V);
  float* wv_ = (float*)(ws + WS_W);
  float* rel = (float*)(ws + WS_REL);
  float* out = (float*)d_out;

  hipLaunchKernelGGL(prep_uv, dim3(NB*O), dim3(256), 0, stream, x, gW0, u, v);
  hipLaunchKernelGGL(prep_wt, dim3(768),  dim3(256), 0, stream, gW1, gW2, gW3, Wt);
  hipLaunchKernelGGL(prep_w,  dim3(NB),   dim3(256), 0, stream, q, gW0, gb0, wv_, rel);
  hipLaunchKernelGGL(rn_main, dim3(NB*NTILES), dim3(256), 0, stream,
                     u, v, wv_, Wt, gb1, gb2, gb3, rel);
  hipLaunchKernelGGL(fphi, dim3(NB), dim3(256), 0, stream,
                     rel, fW0, fb0, fW1, fb1, fW2, fb2, out);
}

// Round 3
// 351.915 us; speedup vs baseline: 1.2732x; 1.2732x over previous
//
#include <hip/hip_runtime.h>
#include <hip/hip_bf16.h>

typedef __attribute__((ext_vector_type(8))) short short8;
typedef __attribute__((ext_vector_type(4))) short short4v;
typedef __attribute__((ext_vector_type(4))) float f32x4;

#define O 144
#define NB 32
#define GT 256
#define NPAIRS 10440   // 144*145/2
#define NTILES 164     // ceil(10440/64)

// workspace byte offsets
#define WS_WT   0u          // 3 * 256*256 bf16, k-tiled panel layout
#define WS_U    393216u     // 32*144*256 bf16 (u + w folded)
#define WS_V    2752512u    // 32*144*256 bf16
#define WS_W    5111808u    // 32*256 f32
#define WS_REL  5144576u    // 32*256 f32

__device__ __forceinline__ float bf2f(unsigned short b){
  unsigned int uu = ((unsigned int)b) << 16;
  return __builtin_bit_cast(float, uu);
}
__device__ __forceinline__ unsigned short f2bf(float f){
  unsigned int uu = __builtin_bit_cast(unsigned int, f);
  unsigned int lsb = (uu >> 16) & 1u;
  uu += 0x7fffu + lsb;               // round-to-nearest-even
  return (unsigned short)(uu >> 16);
}

// ---- prep: w[n,:] = q[n] . gW0[52:180,:] + gb0 ; zero rel ----
__global__ void prep_w(const float* __restrict__ q, const float* __restrict__ gW0,
                       const float* __restrict__ gb0, float* __restrict__ wv_,
                       float* __restrict__ rel){
  int n = blockIdx.x, t = threadIdx.x;
  __shared__ float ql[128];
  if (t < 128) ql[t] = q[n*128 + t];
  __syncthreads();
  float s = gb0[t];
  for (int d = 0; d < 128; d++) s += ql[d] * gW0[(52 + d)*GT + t];
  wv_[n*GT + t] = s;
  rel[n*GT + t] = 0.f;
}

// ---- prep: u[n,o,:] = feats(n,o).gW0[0:26,:] + w[n,:],  v = feats.gW0[26:52,:] ----
__global__ void prep_uv(const float* __restrict__ x, const float* __restrict__ gW0,
                        const float* __restrict__ wv_,
                        unsigned short* __restrict__ u, unsigned short* __restrict__ v){
  int blk = blockIdx.x;
  int n = blk / O, o = blk % O;
  __shared__ float f[26];
  int t = threadIdx.x;
  if (t < 24) f[t] = x[(n*24 + t)*144 + o];
  if (t == 24) f[24] = -1.f + 2.f * (float)(o / 12) / 11.f;  // xc (row coord)
  if (t == 25) f[25] = -1.f + 2.f * (float)(o % 12) / 11.f;  // yc (col coord)
  __syncthreads();
  float su = 0.f, sv = 0.f;
  #pragma unroll
  for (int c = 0; c < 26; c++){
    float fc = f[c];
    su += fc * gW0[c*GT + t];
    sv += fc * gW0[(26 + c)*GT + t];
  }
  u[(n*O + o)*GT + t] = f2bf(su + wv_[n*GT + t]);
  v[(n*O + o)*GT + t] = f2bf(sv);
}

// ---- prep: k-tiled panel layout so one wave A-load = 1KB contiguous ----
// WtP[l][et*4096 + kk*512 + r*32 + g*8 + d] = W_l[k = kk*32+g*8+d][e = et*16+r]
__global__ void prep_wt(const float* __restrict__ gW1, const float* __restrict__ gW2,
                        const float* __restrict__ gW3, unsigned short* __restrict__ WtP){
  int li = blockIdx.x >> 8;
  int e  = blockIdx.x & 255;
  int k  = threadIdx.x;
  const float* W = (li == 0) ? gW1 : (li == 1) ? gW2 : gW3;
  int et = e >> 4, r = e & 15;
  int kk = k >> 5, g = (k >> 3) & 3, d = k & 7;
  WtP[li*65536 + et*4096 + kk*512 + r*32 + g*8 + d] = f2bf(W[k*GT + e]);
}

// ---- main fused kernel: h0 build + 3 MFMA layers (swapped operands) + sum ----
__global__ __launch_bounds__(256, 3) void rn_main(
    const unsigned short* __restrict__ u, const unsigned short* __restrict__ v,
    const unsigned short* __restrict__ WtP,
    const float* __restrict__ gb1, const float* __restrict__ gb2,
    const float* __restrict__ gb3, float* __restrict__ rel)
{
  __shared__ short8 hbuf[2048];          // 64 rows x 256 cols bf16, XOR-swizzled
  char* lds = (char*)hbuf;

  const int tid  = threadIdx.x;
  const int lane = tid & 63;
  const int wav  = tid >> 6;             // 0..3, owns output features [wav*64, +64)
  const int n    = blockIdx.x / NTILES;
  const int tile = blockIdx.x - n*NTILES;
  const int tbase = tile * 64;

  // ---- stage h0 = relu(u'[n,b] + v[n,a]), row r <-> pair tbase+r ----
  {
    int r  = tid >> 2;
    int pt = tbase + r;
    bool valid = pt < NPAIRS;
    int pa = 0, pb = 0;
    if (valid){
      pa = (int)((sqrtf(8.f*(float)pt + 1.f) - 1.f) * 0.5f);
      while ((pa + 1)*(pa + 2)/2 <= pt) pa++;
      while (pa*(pa + 1)/2 > pt) pa--;
      pb = pt - pa*(pa + 1)/2;
    }
    const unsigned short* up = u + (size_t)(n*O + pb)*GT;
    const unsigned short* vp = v + (size_t)(n*O + pa)*GT;
    int c0 = (tid & 3) * 64;
    #pragma unroll
    for (int cc = 0; cc < 64; cc += 8){
      int col = c0 + cc;
      short8 hv;
      if (valid){
        short8 uu = *(const short8*)(up + col);
        short8 vv = *(const short8*)(vp + col);
        #pragma unroll
        for (int j = 0; j < 8; j++){
          float s = bf2f((unsigned short)uu[j]) + bf2f((unsigned short)vv[j]);
          hv[j] = (short)f2bf(fmaxf(s, 0.f));
        }
      } else {
        #pragma unroll
        for (int j = 0; j < 8; j++) hv[j] = 0;
      }
      *(short8*)(lds + r*512 + (((col*2) ^ ((r & 7) << 4)))) = hv;
    }
  }
  __syncthreads();

  const int l15 = lane & 15, l4 = lane >> 4;
  const bool fullvalid = (tbase + 64 <= NPAIRS);
  f32x4 acc[4][4];

  #pragma unroll
  for (int L = 0; L < 3; L++){
    // A (WtP): per-lane base; +ie*4096 +kk*512 gives contiguous coalesced 1KB/wave
    const unsigned short* Wl = WtP + L*65536 + wav*4*4096 + l15*32 + l4*8;
    const float* gb = (L == 0) ? gb1 : (L == 1) ? gb2 : gb3;

    #pragma unroll
    for (int ie = 0; ie < 4; ie++)
      #pragma unroll
      for (int jp = 0; jp < 4; jp++)
        acc[ie][jp] = (f32x4){0.f, 0.f, 0.f, 0.f};

    #pragma unroll
    for (int kk = 0; kk < 8; kk++){
      short8 a[4], b[4];
      #pragma unroll
      for (int ie = 0; ie < 4; ie++)
        a[ie] = *(const short8*)(Wl + ie*4096 + kk*512);
      #pragma unroll
      for (int jp = 0; jp < 4; jp++){
        int row = jp*16 + l15;
        b[jp] = *(short8*)(lds + row*512 + ((kk*64 + l4*16) ^ ((row & 7) << 4)));
      }
      #pragma unroll
      for (int ie = 0; ie < 4; ie++)
        #pragma unroll
        for (int jp = 0; jp < 4; jp++)
          acc[ie][jp] = __builtin_amdgcn_mfma_f32_16x16x32_bf16(a[ie], b[jp], acc[ie][jp], 0, 0, 0);
    }

    if (L < 2){
      __syncthreads();                   // all waves done reading h_in
      #pragma unroll
      for (int ie = 0; ie < 4; ie++){
        int e0 = wav*64 + ie*16 + l4*4;  // 4 consecutive output features
        f32x4 bb = *(const f32x4*)(gb + e0);
        #pragma unroll
        for (int jp = 0; jp < 4; jp++){
          int row = jp*16 + l15;         // pair row
          short4v pk;
          #pragma unroll
          for (int j = 0; j < 4; j++)
            pk[j] = (short)f2bf(fmaxf(acc[ie][jp][j] + bb[j], 0.f));
          *(short4v*)(lds + row*512 + ((e0*2) ^ ((row & 7) << 4))) = pk;
        }
      }
      __syncthreads();                   // h_out visible to all waves
    } else {
      // layer 3: bias+relu, mask tail pairs, sum over pairs -> atomic into rel
      #pragma unroll
      for (int ie = 0; ie < 4; ie++){
        int e0 = wav*64 + ie*16 + l4*4;
        f32x4 bb = *(const f32x4*)(gb + e0);
        f32x4 s = {0.f, 0.f, 0.f, 0.f};
        #pragma unroll
        for (int jp = 0; jp < 4; jp++){
          bool pv = fullvalid || (tbase + jp*16 + l15 < NPAIRS);
          #pragma unroll
          for (int j = 0; j < 4; j++){
            float hvv = fmaxf(acc[ie][jp][j] + bb[j], 0.f);
            s[j] += pv ? hvv : 0.f;
          }
        }
        #pragma unroll
        for (int st = 1; st < 16; st <<= 1){
          #pragma unroll
          for (int j = 0; j < 4; j++)
            s[j] += __shfl_xor(s[j], st);
        }
        if (l15 == 0){
          #pragma unroll
          for (int j = 0; j < 4; j++)
            atomicAdd(&rel[n*GT + e0 + j], s[j]);
        }
      }
    }
  }
}

// ---- f_phi: per-batch 256->256->256->28, f32 ----
__global__ void fphi(const float* __restrict__ rel,
                     const float* __restrict__ fW0, const float* __restrict__ fb0,
                     const float* __restrict__ fW1, const float* __restrict__ fb1,
                     const float* __restrict__ fW2, const float* __restrict__ fb2,
                     float* __restrict__ out){
  int n = blockIdx.x, t = threadIdx.x;
  __shared__ float h[256], y[256];
  h[t] = rel[n*GT + t];
  __syncthreads();
  float s = fb0[t];
  for (int k = 0; k < 256; k++) s += h[k] * fW0[k*GT + t];
  y[t] = fmaxf(s, 0.f);
  __syncthreads();
  s = fb1[t];
  for (int k = 0; k < 256; k++) s += y[k] * fW1[k*GT + t];
  __syncthreads();                 // everyone done reading y; safe to reuse h
  h[t] = fmaxf(s, 0.f);
  __syncthreads();
  if (t < 28){
    s = fb2[t];
    for (int k = 0; k < 256; k++) s += h[k] * fW2[k*28 + t];
    out[n*28 + t] = s;
  }
}

extern "C" void kernel_launch(void* const* d_in, const int* in_sizes, int n_in,
                              void* d_out, int out_size, void* d_ws, size_t ws_size,
                              hipStream_t stream){
  (void)in_sizes; (void)n_in; (void)out_size; (void)ws_size;
  const float* x   = (const float*)d_in[0];
  const float* q   = (const float*)d_in[1];
  const float* gW0 = (const float*)d_in[2];
  const float* gb0 = (const float*)d_in[3];
  const float* gW1 = (const float*)d_in[4];
  const float* gb1 = (const float*)d_in[5];
  const float* gW2 = (const float*)d_in[6];
  const float* gb2 = (const float*)d_in[7];
  const float* gW3 = (const float*)d_in[8];
  const float* gb3 = (const float*)d_in[9];
  const float* fW0 = (const float*)d_in[10];
  const float* fb0 = (const float*)d_in[11];
  const float* fW1 = (const float*)d_in[12];
  const float* fb1 = (const float*)d_in[13];
  const float* fW2 = (const float*)d_in[14];
  const float* fb2 = (const float*)d_in[15];

  char* ws = (char*)d_ws;
  unsigned short* WtP = (unsigned short*)(ws + WS_WT);
  unsigned short* u   = (unsigned short*)(ws + WS_U);
  unsigned short* v   = (unsigned short*)(ws + WS_V);
  float* wv_ = (float*)(ws + WS_W);
  float* rel = (float*)(ws + WS_REL);
  float* out = (float*)d_out;

  hipLaunchKernelGGL(prep_w,  dim3(NB),   dim3(256), 0, stream, q, gW0, gb0, wv_, rel);
  hipLaunchKernelGGL(prep_uv, dim3(NB*O), dim3(256), 0, stream, x, gW0, wv_, u, v);
  hipLaunchKernelGGL(prep_wt, dim3(768),  dim3(256), 0, stream, gW1, gW2, gW3, WtP);
  hipLaunchKernelGGL(rn_main, dim3(NB*NTILES), dim3(256), 0, stream,
                     u, v, WtP, gb1, gb2, gb3, rel);
  hipLaunchKernelGGL(fphi, dim3(NB), dim3(256), 0, stream,
                     rel, fW0, fb0, fW1, fb1, fW2, fb2, out);
}

// Round 4
// 297.203 us; speedup vs baseline: 1.5075x; 1.1841x over previous
//
#include <hip/hip_runtime.h>
#include <hip/hip_bf16.h>

typedef __attribute__((ext_vector_type(8))) short short8;
typedef __attribute__((ext_vector_type(4))) short short4v;
typedef __attribute__((ext_vector_type(4))) float f32x4;

#define O 144
#define NB 32
#define GT 256
#define NPAIRS 10440   // 144*145/2
#define TP 128         // pairs per rn_main block
#define NT 82          // ceil(10440/128)

// workspace byte offsets
#define WS_WT   0u          // 3 * 256*256 bf16, k-tiled panel layout
#define WS_U    393216u     // 32*144*256 bf16 (u + w + gb0 folded)
#define WS_V    2752512u    // 32*144*256 bf16
#define WS_REL  5144576u    // 32*256 f32

// XOR swizzle: fold row bits AND colb bits 7-8 into bank-slot bits 4-6.
// colb in [0,512); result stays in [0,512).
#define SWZ(row, colb) ((colb) ^ (((row) & 7) << 4) ^ ((((colb) >> 2) & 0x60)))

__device__ __forceinline__ float bf2f(unsigned short b){
  unsigned int uu = ((unsigned int)b) << 16;
  return __builtin_bit_cast(float, uu);
}
__device__ __forceinline__ unsigned short f2bf(float f){
  unsigned int uu = __builtin_bit_cast(unsigned int, f);
  unsigned int lsb = (uu >> 16) & 1u;
  uu += 0x7fffu + lsb;               // round-to-nearest-even
  return (unsigned short)(uu >> 16);
}

// ---- merged prep: blocks [0,4608) build u/v (w,gb0 folded into u);
//      blocks [4608,5376) transpose W1..W3 into k-tiled panels; first 32 zero rel
__global__ void prep_all(const float* __restrict__ x, const float* __restrict__ q,
                         const float* __restrict__ gW0, const float* __restrict__ gb0,
                         const float* __restrict__ gW1, const float* __restrict__ gW2,
                         const float* __restrict__ gW3,
                         unsigned short* __restrict__ u, unsigned short* __restrict__ v,
                         unsigned short* __restrict__ WtP, float* __restrict__ rel){
  int blk = blockIdx.x, t = threadIdx.x;
  if (blk < NB*O){
    int n = blk / O, o = blk - n*O;
    __shared__ float f[26];
    __shared__ float ql[128];
    if (t < 24) f[t] = x[(n*24 + t)*144 + o];
    if (t == 24) f[24] = -1.f + 2.f * (float)(o / 12) / 11.f;  // xc
    if (t == 25) f[25] = -1.f + 2.f * (float)(o % 12) / 11.f;  // yc
    if (t >= 128) ql[t - 128] = q[n*128 + (t - 128)];
    __syncthreads();
    float su = gb0[t], sv = 0.f;
    for (int d = 0; d < 128; d++) su += ql[d] * gW0[(52 + d)*GT + t];
    #pragma unroll
    for (int c = 0; c < 26; c++){
      float fc = f[c];
      su += fc * gW0[c*GT + t];
      sv += fc * gW0[(26 + c)*GT + t];
    }
    u[(size_t)(n*O + o)*GT + t] = f2bf(su);
    v[(size_t)(n*O + o)*GT + t] = f2bf(sv);
  } else {
    int b2 = blk - NB*O;               // 0..767
    int li = b2 >> 8, e = b2 & 255;
    const float* W = (li == 0) ? gW1 : (li == 1) ? gW2 : gW3;
    int et = e >> 4, r = e & 15;
    int kk = t >> 5, g = (t >> 3) & 3, d = t & 7;
    WtP[li*65536 + et*4096 + kk*512 + r*32 + g*8 + d] = f2bf(W[t*GT + e]);
    if (b2 < NB) rel[b2*GT + t] = 0.f;
  }
}

// ---- main fused kernel: 128 pairs/block, 3 MFMA layers, A-prefetch pipeline ----
__global__ __launch_bounds__(256, 2) void rn_main(
    const unsigned short* __restrict__ u, const unsigned short* __restrict__ v,
    const unsigned short* __restrict__ WtP,
    const float* __restrict__ gb1, const float* __restrict__ gb2,
    const float* __restrict__ gb3, float* __restrict__ rel)
{
  __shared__ short8 hbuf[4096];        // 128 rows x 256 cols bf16, swizzled
  char* lds = (char*)hbuf;

  const int tid  = threadIdx.x;
  const int lane = tid & 63;
  const int wav  = tid >> 6;           // 0..3, owns output features [wav*64, +64)
  const int n    = blockIdx.x / NT;
  const int tile = blockIdx.x - n*NT;
  const int tbase = tile * TP;
  const int l15 = lane & 15, l4 = lane >> 4;

  // A-prefetch: phase p = L*8+kk in [0,24); 4 feature-subtiles per wave
  const unsigned short* wbase = WtP + wav*16384 + l15*32 + l4*8;
  short8 an0, an1, an2, an3;
#define LOADA(p_) { const unsigned short* _wp = wbase + ((p_) >> 3)*65536 + ((p_) & 7)*512; \
    an0 = *(const short8*)(_wp);         an1 = *(const short8*)(_wp + 4096);               \
    an2 = *(const short8*)(_wp + 8192);  an3 = *(const short8*)(_wp + 12288); }
  LOADA(0);                            // in flight during staging

  // ---- stage h0 = relu(u'[n,b] + v[n,a]); quarter-wave covers 16 distinct rows ----
  {
    int row = wav*32 + (lane >> 1);    // 2 lanes per row
    int pt  = tbase + row;
    bool valid = pt < NPAIRS;
    int pa = 0, pb = 0;
    if (valid){
      pa = (int)((sqrtf(8.f*(float)pt + 1.f) - 1.f) * 0.5f);
      while ((pa + 1)*(pa + 2)/2 <= pt) pa++;
      while (pa*(pa + 1)/2 > pt) pa--;
      pb = pt - pa*(pa + 1)/2;
    }
    const unsigned short* up = u + (size_t)(n*O + pb)*GT;
    const unsigned short* vp = v + (size_t)(n*O + pa)*GT;
    int cbase = (lane & 1) * 128;
    #pragma unroll
    for (int cc = 0; cc < 16; cc++){
      int col = cbase + cc*8;
      short8 hv;
      if (valid){
        short8 uu = *(const short8*)(up + col);
        short8 vv = *(const short8*)(vp + col);
        #pragma unroll
        for (int j = 0; j < 8; j++){
          float s = bf2f((unsigned short)uu[j]) + bf2f((unsigned short)vv[j]);
          hv[j] = (short)f2bf(fmaxf(s, 0.f));
        }
      } else {
        #pragma unroll
        for (int j = 0; j < 8; j++) hv[j] = 0;
      }
      *(short8*)(lds + row*512 + SWZ(row, col*2)) = hv;
    }
  }
  __syncthreads();

  const bool fullvalid = (tbase + TP <= NPAIRS);
  f32x4 acc[4][8];

  #pragma unroll
  for (int L = 0; L < 3; L++){
    const float* gb = (L == 0) ? gb1 : (L == 1) ? gb2 : gb3;

    // init accumulators with bias (row e = wav*64 + ie*16 + l4*4 + j)
    #pragma unroll
    for (int ie = 0; ie < 4; ie++){
      f32x4 bbv = *(const f32x4*)(gb + wav*64 + ie*16 + l4*4);
      #pragma unroll
      for (int jp = 0; jp < 8; jp++) acc[ie][jp] = bbv;
    }

    #pragma unroll
    for (int kk = 0; kk < 8; kk++){
      short8 a0 = an0, a1 = an1, a2 = an2, a3 = an3;
      int pn = L*8 + kk + 1; if (pn > 23) pn = 23;   // compile-time per unrolled iter
      LOADA(pn);                                     // next phase's A in flight
      short8 b[8];
      #pragma unroll
      for (int jp = 0; jp < 8; jp++){
        int row = jp*16 + l15;
        b[jp] = *(short8*)(lds + row*512 + SWZ(row, kk*64 + l4*16));
      }
      #pragma unroll
      for (int jp = 0; jp < 8; jp++){
        acc[0][jp] = __builtin_amdgcn_mfma_f32_16x16x32_bf16(a0, b[jp], acc[0][jp], 0, 0, 0);
        acc[1][jp] = __builtin_amdgcn_mfma_f32_16x16x32_bf16(a1, b[jp], acc[1][jp], 0, 0, 0);
        acc[2][jp] = __builtin_amdgcn_mfma_f32_16x16x32_bf16(a2, b[jp], acc[2][jp], 0, 0, 0);
        acc[3][jp] = __builtin_amdgcn_mfma_f32_16x16x32_bf16(a3, b[jp], acc[3][jp], 0, 0, 0);
      }
    }

    if (L < 2){
      __syncthreads();                 // all waves done reading h_in
      #pragma unroll
      for (int ie = 0; ie < 4; ie++){
        int colb = (wav*64 + ie*16 + l4*4) * 2;
        #pragma unroll
        for (int jp = 0; jp < 8; jp++){
          int row = jp*16 + l15;
          short4v pk;
          #pragma unroll
          for (int j = 0; j < 4; j++)
            pk[j] = (short)f2bf(fmaxf(acc[ie][jp][j], 0.f));
          *(short4v*)(lds + row*512 + SWZ(row, colb)) = pk;
        }
      }
      __syncthreads();                 // h_out visible to all waves
    } else {
      // layer 3: relu, mask tail pairs, sum over pairs -> atomic into rel
      #pragma unroll
      for (int ie = 0; ie < 4; ie++){
        int e0 = wav*64 + ie*16 + l4*4;
        f32x4 s = {0.f, 0.f, 0.f, 0.f};
        #pragma unroll
        for (int jp = 0; jp < 8; jp++){
          bool pv = fullvalid || (tbase + jp*16 + l15 < NPAIRS);
          #pragma unroll
          for (int j = 0; j < 4; j++){
            float hvv = fmaxf(acc[ie][jp][j], 0.f);
            s[j] += pv ? hvv : 0.f;
          }
        }
        #pragma unroll
        for (int st = 1; st < 16; st <<= 1){
          #pragma unroll
          for (int j = 0; j < 4; j++)
            s[j] += __shfl_xor(s[j], st);
        }
        if (l15 == 0){
          #pragma unroll
          for (int j = 0; j < 4; j++)
            atomicAdd(&rel[n*GT + e0 + j], s[j]);
        }
      }
    }
  }
#undef LOADA
}

// ---- f_phi: per-batch 256->256->256->28, f32 ----
__global__ void fphi(const float* __restrict__ rel,
                     const float* __restrict__ fW0, const float* __restrict__ fb0,
                     const float* __restrict__ fW1, const float* __restrict__ fb1,
                     const float* __restrict__ fW2, const float* __restrict__ fb2,
                     float* __restrict__ out){
  int n = blockIdx.x, t = threadIdx.x;
  __shared__ float h[256], y[256];
  h[t] = rel[n*GT + t];
  __syncthreads();
  float s = fb0[t];
  for (int k = 0; k < 256; k++) s += h[k] * fW0[k*GT + t];
  y[t] = fmaxf(s, 0.f);
  __syncthreads();
  s = fb1[t];
  for (int k = 0; k < 256; k++) s += y[k] * fW1[k*GT + t];
  __syncthreads();                 // everyone done reading y; safe to reuse h
  h[t] = fmaxf(s, 0.f);
  __syncthreads();
  if (t < 28){
    s = fb2[t];
    for (int k = 0; k < 256; k++) s += h[k] * fW2[k*28 + t];
    out[n*28 + t] = s;
  }
}

extern "C" void kernel_launch(void* const* d_in, const int* in_sizes, int n_in,
                              void* d_out, int out_size, void* d_ws, size_t ws_size,
                              hipStream_t stream){
  (void)in_sizes; (void)n_in; (void)out_size; (void)ws_size;
  const float* x   = (const float*)d_in[0];
  const float* q   = (const float*)d_in[1];
  const float* gW0 = (const float*)d_in[2];
  const float* gb0 = (const float*)d_in[3];
  const float* gW1 = (const float*)d_in[4];
  const float* gb1 = (const float*)d_in[5];
  const float* gW2 = (const float*)d_in[6];
  const float* gb2 = (const float*)d_in[7];
  const float* gW3 = (const float*)d_in[8];
  const float* gb3 = (const float*)d_in[9];
  const float* fW0 = (const float*)d_in[10];
  const float* fb0 = (const float*)d_in[11];
  const float* fW1 = (const float*)d_in[12];
  const float* fb1 = (const float*)d_in[13];
  const float* fW2 = (const float*)d_in[14];
  const float* fb2 = (const float*)d_in[15];

  char* ws = (char*)d_ws;
  unsigned short* WtP = (unsigned short*)(ws + WS_WT);
  unsigned short* u   = (unsigned short*)(ws + WS_U);
  unsigned short* v   = (unsigned short*)(ws + WS_V);
  float* rel = (float*)(ws + WS_REL);
  float* out = (float*)d_out;

  hipLaunchKernelGGL(prep_all, dim3(NB*O + 768), dim3(256), 0, stream,
                     x, q, gW0, gb0, gW1, gW2, gW3, u, v, WtP, rel);
  hipLaunchKernelGGL(rn_main, dim3(NB*NT), dim3(256), 0, stream,
                     u, v, WtP, gb1, gb2, gb3, rel);
  hipLaunchKernelGGL(fphi, dim3(NB), dim3(256), 0, stream,
                     rel, fW0, fb0, fW1, fb1, fW2, fb2, out);
}

// Round 5
// 270.213 us; speedup vs baseline: 1.6581x; 1.0999x over previous
//
#include <hip/hip_runtime.h>
#include <hip/hip_bf16.h>

typedef __attribute__((ext_vector_type(8))) short short8;
typedef __attribute__((ext_vector_type(4))) float f32x4;

#define O 144
#define NB 32
#define GT 256
#define NPAIRS 10440   // 144*145/2
#define TP 128         // pairs per rn_main block
#define NT 82          // ceil(10440/128)

// workspace byte offsets
#define WS_WT   0u          // 3 * 256*256 bf16, k-tiled panel layout
#define WS_U    393216u     // 32*144*256 bf16 (u + wq + gb0 folded)
#define WS_V    2752512u    // 32*144*256 bf16
#define WS_REL  5144576u    // 32*256 f32

__device__ __forceinline__ float bf2f(unsigned short b){
  unsigned int uu = ((unsigned int)b) << 16;
  return __builtin_bit_cast(float, uu);
}
__device__ __forceinline__ unsigned short f2bf(float f){
  unsigned int uu = __builtin_bit_cast(unsigned int, f);
  unsigned int lsb = (uu >> 16) & 1u;
  uu += 0x7fffu + lsb;               // round-to-nearest-even
  return (unsigned short)(uu >> 16);
}
// HW packed f32->bf16 (RNE), 2 elements in 1 instr
__device__ __forceinline__ unsigned int cvtpk(float lo, float hi){
  unsigned int r;
  asm("v_cvt_pk_bf16_f32 %0, %1, %2" : "=v"(r) : "v"(lo), "v"(hi));
  return r;
}

// ---- prep_uv: 128 blocks = (n, o-quad). q-dot computed once per thread. ----
__global__ void prep_uv(const float* __restrict__ x, const float* __restrict__ q,
                        const float* __restrict__ gW0, const float* __restrict__ gb0,
                        unsigned short* __restrict__ u, unsigned short* __restrict__ v){
  __shared__ float xs[24][36];
  __shared__ float qs[128];
  int n = blockIdx.x >> 2, oq = blockIdx.x & 3;
  int t = threadIdx.x;
  int o0 = oq * 36;
  for (int i = t; i < 864; i += 256){
    int c = i / 36, oo = i - c*36;
    xs[c][oo] = x[(n*24 + c)*144 + o0 + oo];
  }
  if (t < 128) qs[t] = q[n*128 + t];
  __syncthreads();
  float wq = gb0[t];
  for (int d = 0; d < 128; d++) wq += qs[d] * gW0[(52 + d)*GT + t];
  float wc[52];
  #pragma unroll
  for (int c = 0; c < 52; c++) wc[c] = gW0[c*GT + t];
  for (int oo = 0; oo < 36; oo++){
    int o = o0 + oo;
    float xc = -1.f + 2.f * (float)(o / 12) / 11.f;
    float yc = -1.f + 2.f * (float)(o % 12) / 11.f;
    float su = wq + xc*wc[24] + yc*wc[25];
    float sv =      xc*wc[50] + yc*wc[51];
    #pragma unroll
    for (int c = 0; c < 24; c++){ float f = xs[c][oo]; su += f*wc[c]; sv += f*wc[26+c]; }
    u[(size_t)(n*O + o)*GT + t] = f2bf(su);
    v[(size_t)(n*O + o)*GT + t] = f2bf(sv);
  }
}

// ---- prep_wt: k-tiled panels; first 32 blocks also zero rel ----
// WtP[l][et*4096 + kk*512 + r*32 + g*8 + d] = W_l[k = kk*32+g*8+d][e = et*16+r]
__global__ void prep_wt(const float* __restrict__ gW1, const float* __restrict__ gW2,
                        const float* __restrict__ gW3, unsigned short* __restrict__ WtP,
                        float* __restrict__ rel){
  int li = blockIdx.x >> 8;
  int e  = blockIdx.x & 255;
  int k  = threadIdx.x;
  const float* W = (li == 0) ? gW1 : (li == 1) ? gW2 : gW3;
  int et = e >> 4, r = e & 15;
  int kk = k >> 5, g = (k >> 3) & 3, d = k & 7;
  WtP[li*65536 + et*4096 + kk*512 + r*32 + g*8 + d] = f2bf(W[k*GT + e]);
  if (blockIdx.x < NB) rel[blockIdx.x*GT + k] = 0.f;
}

// ---- main fused kernel ----
// LDS h layout: h[row][col] bf16 at byte  row*512 + ((col*2) ^ ((row&3)<<4))
__global__ __launch_bounds__(256, 2) void rn_main(
    const unsigned short* __restrict__ u, const unsigned short* __restrict__ v,
    const unsigned short* __restrict__ WtP,
    const float* __restrict__ gb1, const float* __restrict__ gb2,
    const float* __restrict__ gb3, float* __restrict__ rel)
{
  __shared__ short8 hbuf[4096];        // 128 rows x 256 cols bf16, swizzled
  char* lds = (char*)hbuf;

  const int tid  = threadIdx.x;
  const int lane = tid & 63;
  const int wav  = tid >> 6;           // 0..3, owns output features [wav*64, +64)
  const int n    = blockIdx.x / NT;
  const int tile = blockIdx.x - n*NT;
  const int tbase = tile * TP;
  const int l15 = lane & 15, l4 = lane >> 4;

  // A-prefetch: phase p = L*8+kk in [0,24)
  const unsigned short* wbase = WtP + wav*16384 + l15*32 + l4*8;
  short8 an0, an1, an2, an3;
#define LOADA(p_) { const unsigned short* _wp = wbase + ((p_) >> 3)*65536 + ((p_) & 7)*512; \
    an0 = *(const short8*)(_wp);         an1 = *(const short8*)(_wp + 4096);               \
    an2 = *(const short8*)(_wp + 8192);  an3 = *(const short8*)(_wp + 12288); }
  LOADA(0);                            // in flight during staging

  // ---- stage h0 = relu(u'[n,b] + v[n,a]); 2 lanes per row ----
  {
    int row = wav*32 + (lane >> 1);
    int pt  = tbase + row;
    bool valid = pt < NPAIRS;
    int pa = 0, pb = 0;
    if (valid){
      pa = (int)((sqrtf(8.f*(float)pt + 1.f) - 1.f) * 0.5f);
      while ((pa + 1)*(pa + 2)/2 <= pt) pa++;
      while (pa*(pa + 1)/2 > pt) pa--;
      pb = pt - pa*(pa + 1)/2;
    }
    const uint4* up4 = (const uint4*)(u + (size_t)(n*O + pb)*GT);
    const uint4* vp4 = (const uint4*)(v + (size_t)(n*O + pa)*GT);
    int half = lane & 1;               // which 128-col half
    int sbase = row*512 + half*256;    // byte base (pre-swizzle)
    int ts = ((lane >> 1) & 3) << 4;   // (row&3)<<4
    #pragma unroll
    for (int cc = 0; cc < 16; cc++){
      uint4 hv;
      if (valid){
        uint4 uu = up4[half*16 + cc];
        uint4 vv = vp4[half*16 + cc];
        #pragma unroll
        for (int j = 0; j < 4; j++){
          unsigned int ud = (&uu.x)[j], vd = (&vv.x)[j];
          float lo = __builtin_bit_cast(float, ud << 16) + __builtin_bit_cast(float, vd << 16);
          float hi = __builtin_bit_cast(float, ud & 0xffff0000u) + __builtin_bit_cast(float, vd & 0xffff0000u);
          (&hv.x)[j] = cvtpk(fmaxf(lo, 0.f), fmaxf(hi, 0.f));
        }
      } else {
        hv = (uint4){0u, 0u, 0u, 0u};
      }
      *(uint4*)(lds + sbase + ((cc*16) ^ ts)) = hv;
    }
  }
  __syncthreads();

  const bool fullvalid = (tbase + TP <= NPAIRS);
  const int tsw = (l15 & 3) << 4;                    // (row&3)<<4 for row = jp*16+l15
  const int rbase = l15*512 + ((l4*16) ^ tsw);       // B-read base; + jp*8192 + kk*64 imm
  const int ebase = l15*512 + wav*128 + ((l4*8) ^ (tsw & 16));  // epilogue base
  f32x4 acc[4][8];

  #pragma unroll
  for (int L = 0; L < 3; L++){
    const float* gb = (L == 0) ? gb1 : (L == 1) ? gb2 : gb3;

    // init accumulators with bias (feature e = wav*64 + ie*16 + l4*4 + j)
    #pragma unroll
    for (int ie = 0; ie < 4; ie++){
      f32x4 bbv = *(const f32x4*)(gb + wav*64 + ie*16 + l4*4);
      #pragma unroll
      for (int jp = 0; jp < 8; jp++) acc[ie][jp] = bbv;
    }

    #pragma unroll
    for (int kk = 0; kk < 8; kk++){
      short8 a0 = an0, a1 = an1, a2 = an2, a3 = an3;
      int pn = L*8 + kk + 1; if (pn > 23) pn = 23;
      LOADA(pn);                                     // next phase's A in flight
      short8 b[8];
      #pragma unroll
      for (int jp = 0; jp < 8; jp++)
        b[jp] = *(short8*)(lds + rbase + jp*8192 + kk*64);
      __builtin_amdgcn_s_setprio(1);
      #pragma unroll
      for (int jp = 0; jp < 8; jp++){
        acc[0][jp] = __builtin_amdgcn_mfma_f32_16x16x32_bf16(a0, b[jp], acc[0][jp], 0, 0, 0);
        acc[1][jp] = __builtin_amdgcn_mfma_f32_16x16x32_bf16(a1, b[jp], acc[1][jp], 0, 0, 0);
        acc[2][jp] = __builtin_amdgcn_mfma_f32_16x16x32_bf16(a2, b[jp], acc[2][jp], 0, 0, 0);
        acc[3][jp] = __builtin_amdgcn_mfma_f32_16x16x32_bf16(a3, b[jp], acc[3][jp], 0, 0, 0);
      }
      __builtin_amdgcn_s_setprio(0);
    }

    if (L < 2){
      __syncthreads();                 // all waves done reading h_in
      #pragma unroll
      for (int ie = 0; ie < 4; ie++){
        int ea = ebase + ((ie*32) ^ (tsw & 32));
        #pragma unroll
        for (int jp = 0; jp < 8; jp++){
          uint2 pk;
          pk.x = cvtpk(fmaxf(acc[ie][jp][0], 0.f), fmaxf(acc[ie][jp][1], 0.f));
          pk.y = cvtpk(fmaxf(acc[ie][jp][2], 0.f), fmaxf(acc[ie][jp][3], 0.f));
          *(uint2*)(lds + ea + jp*8192) = pk;
        }
      }
      __syncthreads();                 // h_out visible to all waves
    } else {
      // layer 3: relu, mask tail pairs, sum over pairs -> atomic into rel
      #pragma unroll
      for (int ie = 0; ie < 4; ie++){
        int e0 = wav*64 + ie*16 + l4*4;
        f32x4 s = {0.f, 0.f, 0.f, 0.f};
        #pragma unroll
        for (int jp = 0; jp < 8; jp++){
          bool pv = fullvalid || (tbase + jp*16 + l15 < NPAIRS);
          #pragma unroll
          for (int j = 0; j < 4; j++){
            float hvv = fmaxf(acc[ie][jp][j], 0.f);
            s[j] += pv ? hvv : 0.f;
          }
        }
        #pragma unroll
        for (int st = 1; st < 16; st <<= 1){
          #pragma unroll
          for (int j = 0; j < 4; j++)
            s[j] += __shfl_xor(s[j], st);
        }
        if (l15 == 0){
          #pragma unroll
          for (int j = 0; j < 4; j++)
            atomicAdd(&rel[n*GT + e0 + j], s[j]);
        }
      }
    }
  }
#undef LOADA
}

// ---- f_phi: per-batch 256->256->256->28, f32 ----
__global__ void fphi(const float* __restrict__ rel,
                     const float* __restrict__ fW0, const float* __restrict__ fb0,
                     const float* __restrict__ fW1, const float* __restrict__ fb1,
                     const float* __restrict__ fW2, const float* __restrict__ fb2,
                     float* __restrict__ out){
  int n = blockIdx.x, t = threadIdx.x;
  __shared__ float h[256], y[256];
  h[t] = rel[n*GT + t];
  __syncthreads();
  float s = fb0[t];
  for (int k = 0; k < 256; k++) s += h[k] * fW0[k*GT + t];
  y[t] = fmaxf(s, 0.f);
  __syncthreads();
  s = fb1[t];
  for (int k = 0; k < 256; k++) s += y[k] * fW1[k*GT + t];
  __syncthreads();
  h[t] = fmaxf(s, 0.f);
  __syncthreads();
  if (t < 28){
    s = fb2[t];
    for (int k = 0; k < 256; k++) s += h[k] * fW2[k*28 + t];
    out[n*28 + t] = s;
  }
}

extern "C" void kernel_launch(void* const* d_in, const int* in_sizes, int n_in,
                              void* d_out, int out_size, void* d_ws, size_t ws_size,
                              hipStream_t stream){
  (void)in_sizes; (void)n_in; (void)out_size; (void)ws_size;
  const float* x   = (const float*)d_in[0];
  const float* q   = (const float*)d_in[1];
  const float* gW0 = (const float*)d_in[2];
  const float* gb0 = (const float*)d_in[3];
  const float* gW1 = (const float*)d_in[4];
  const float* gb1 = (const float*)d_in[5];
  const float* gW2 = (const float*)d_in[6];
  const float* gb2 = (const float*)d_in[7];
  const float* gW3 = (const float*)d_in[8];
  const float* gb3 = (const float*)d_in[9];
  const float* fW0 = (const float*)d_in[10];
  const float* fb0 = (const float*)d_in[11];
  const float* fW1 = (const float*)d_in[12];
  const float* fb1 = (const float*)d_in[13];
  const float* fW2 = (const float*)d_in[14];
  const float* fb2 = (const float*)d_in[15];

  char* ws = (char*)d_ws;
  unsigned short* WtP = (unsigned short*)(ws + WS_WT);
  unsigned short* u   = (unsigned short*)(ws + WS_U);
  unsigned short* v   = (unsigned short*)(ws + WS_V);
  float* rel = (float*)(ws + WS_REL);
  float* out = (float*)d_out;

  hipLaunchKernelGGL(prep_uv, dim3(NB*4), dim3(256), 0, stream, x, q, gW0, gb0, u, v);
  hipLaunchKernelGGL(prep_wt, dim3(768),  dim3(256), 0, stream, gW1, gW2, gW3, WtP, rel);
  hipLaunchKernelGGL(rn_main, dim3(NB*NT), dim3(256), 0, stream,
                     u, v, WtP, gb1, gb2, gb3, rel);
  hipLaunchKernelGGL(fphi, dim3(NB), dim3(256), 0, stream,
                     rel, fW0, fb0, fW1, fb1, fW2, fb2, out);
}

// Round 6
// 255.712 us; speedup vs baseline: 1.7521x; 1.0567x over previous
//
#include <hip/hip_runtime.h>
#include <hip/hip_bf16.h>

typedef __attribute__((ext_vector_type(8))) short short8;
typedef __attribute__((ext_vector_type(4))) float f32x4;

#define O 144
#define NB 32
#define GT 256
#define NPAIRS 10440   // 144*145/2
#define TP 128         // pairs per rn_main block
#define NT 82          // ceil(10440/128)

// workspace byte offsets
#define WS_WT   0u          // 3 * 256*256 bf16, k-tiled panel layout
#define WS_U    393216u     // 32*144*256 bf16 (u + wq + gb0 folded)
#define WS_V    2752512u    // 32*144*256 bf16
#define WS_REL  5144576u    // 32*256 f32

__device__ __forceinline__ unsigned short f2bf(float f){
  unsigned int uu = __builtin_bit_cast(unsigned int, f);
  unsigned int lsb = (uu >> 16) & 1u;
  uu += 0x7fffu + lsb;               // round-to-nearest-even
  return (unsigned short)(uu >> 16);
}
// HW packed f32->bf16 (RNE), 2 elements in 1 instr
__device__ __forceinline__ unsigned int cvtpk(float lo, float hi){
  unsigned int r;
  asm("v_cvt_pk_bf16_f32 %0, %1, %2" : "=v"(r) : "v"(lo), "v"(hi));
  return r;
}

// ---- prep_uv: 256 blocks = (n, o-octant). q-dot computed once per thread. ----
__global__ void prep_uv(const float* __restrict__ x, const float* __restrict__ q,
                        const float* __restrict__ gW0, const float* __restrict__ gb0,
                        unsigned short* __restrict__ u, unsigned short* __restrict__ v){
  __shared__ float xs[24][18];
  __shared__ float qs[128];
  int n = blockIdx.x >> 3, oq = blockIdx.x & 7;
  int t = threadIdx.x;
  int o0 = oq * 18;
  for (int i = t; i < 432; i += 256){
    int c = i / 18, oo = i - c*18;
    xs[c][oo] = x[(n*24 + c)*144 + o0 + oo];
  }
  if (t < 128) qs[t] = q[n*128 + t];
  __syncthreads();
  float wq = gb0[t];
  for (int d = 0; d < 128; d++) wq += qs[d] * gW0[(52 + d)*GT + t];
  float wc[52];
  #pragma unroll
  for (int c = 0; c < 52; c++) wc[c] = gW0[c*GT + t];
  for (int oo = 0; oo < 18; oo++){
    int o = o0 + oo;
    float xc = -1.f + 2.f * (float)(o / 12) / 11.f;
    float yc = -1.f + 2.f * (float)(o % 12) / 11.f;
    float su = wq + xc*wc[24] + yc*wc[25];
    float sv =      xc*wc[50] + yc*wc[51];
    #pragma unroll
    for (int c = 0; c < 24; c++){ float f = xs[c][oo]; su += f*wc[c]; sv += f*wc[26+c]; }
    u[(size_t)(n*O + o)*GT + t] = f2bf(su);
    v[(size_t)(n*O + o)*GT + t] = f2bf(sv);
  }
}

// ---- prep_wt: k-tiled panels; first 32 blocks also zero rel ----
// WtP[l][et*4096 + kk*512 + r*32 + g*8 + d] = W_l[k = kk*32+g*8+d][e = et*16+r]
__global__ void prep_wt(const float* __restrict__ gW1, const float* __restrict__ gW2,
                        const float* __restrict__ gW3, unsigned short* __restrict__ WtP,
                        float* __restrict__ rel){
  int li = blockIdx.x >> 8;
  int e  = blockIdx.x & 255;
  int k  = threadIdx.x;
  const float* W = (li == 0) ? gW1 : (li == 1) ? gW2 : gW3;
  int et = e >> 4, r = e & 15;
  int kk = k >> 5, g = (k >> 3) & 3, d = k & 7;
  WtP[li*65536 + et*4096 + kk*512 + r*32 + g*8 + d] = f2bf(W[k*GT + e]);
  if (blockIdx.x < NB) rel[blockIdx.x*GT + k] = 0.f;
}

// ---- main fused kernel ----
// LDS h layout: h[row][col] bf16 at byte  row*512 + ((col*2) ^ ((row&7)<<4))
__global__ __launch_bounds__(256, 2) void rn_main(
    const unsigned short* __restrict__ u, const unsigned short* __restrict__ v,
    const unsigned short* __restrict__ WtP,
    const float* __restrict__ gb1, const float* __restrict__ gb2,
    const float* __restrict__ gb3, float* __restrict__ rel)
{
  __shared__ short8 hbuf[4096];        // 128 rows x 256 cols bf16, swizzled
  char* lds = (char*)hbuf;

  const int tid  = threadIdx.x;
  const int lane = tid & 63;
  const int wav  = tid >> 6;           // 0..3, owns output features [wav*64, +64)
  const int n    = blockIdx.x / NT;
  const int tile = blockIdx.x - n*NT;
  const int tbase = tile * TP;
  const int l15 = lane & 15, l4 = lane >> 4;

  // A-prefetch: phase p = L*8+kk in [0,24)
  const unsigned short* wbase = WtP + wav*16384 + l15*32 + l4*8;
  short8 an0, an1, an2, an3;
#define LOADA(p_) { const unsigned short* _wp = wbase + ((p_) >> 3)*65536 + ((p_) & 7)*512; \
    an0 = *(const short8*)(_wp);         an1 = *(const short8*)(_wp + 4096);               \
    an2 = *(const short8*)(_wp + 8192);  an3 = *(const short8*)(_wp + 12288); }
  LOADA(0);                            // in flight during staging

  // ---- stage h0 = relu(u'[n,b] + v[n,a]); 2 lanes per row ----
  {
    int row = wav*32 + (lane >> 1);
    int pt  = tbase + row;
    bool valid = pt < NPAIRS;
    int pa = 0, pb = 0;
    if (valid){
      pa = (int)((sqrtf(8.f*(float)pt + 1.f) - 1.f) * 0.5f);
      while ((pa + 1)*(pa + 2)/2 <= pt) pa++;
      while (pa*(pa + 1)/2 > pt) pa--;
      pb = pt - pa*(pa + 1)/2;
    }
    const uint4* up4 = (const uint4*)(u + (size_t)(n*O + pb)*GT);
    const uint4* vp4 = (const uint4*)(v + (size_t)(n*O + pa)*GT);
    int half = lane & 1;               // which 128-col half
    int sbase = row*512 + half*256;    // byte base (pre-swizzle)
    int ts = ((lane >> 1) & 7) << 4;   // (row&7)<<4
    #pragma unroll
    for (int cc = 0; cc < 16; cc++){
      uint4 hv;
      if (valid){
        uint4 uu = up4[half*16 + cc];
        uint4 vv = vp4[half*16 + cc];
        #pragma unroll
        for (int j = 0; j < 4; j++){
          unsigned int ud = (&uu.x)[j], vd = (&vv.x)[j];
          float lo = __builtin_bit_cast(float, ud << 16) + __builtin_bit_cast(float, vd << 16);
          float hi = __builtin_bit_cast(float, ud & 0xffff0000u) + __builtin_bit_cast(float, vd & 0xffff0000u);
          (&hv.x)[j] = cvtpk(fmaxf(lo, 0.f), fmaxf(hi, 0.f));
        }
      } else {
        hv = (uint4){0u, 0u, 0u, 0u};
      }
      *(uint4*)(lds + sbase + ((cc*16) ^ ts)) = hv;
    }
  }
  __syncthreads();

  const bool fullvalid = (tbase + TP <= NPAIRS);
  // B-read bases: true byte = jp*8192 + l15*512 + ((kk*64 + l4*16) ^ ((l15&7)<<4))
  //  = base(kk-parity) + jp*8192 + kk*64   (bit6 xor -> +/-64 by kk parity)
  const int swz01 = (l15 & 3) << 4;
  const int swz2  = (l15 & 4) << 4;          // 0 or 64
  const int rbE = l15*512 + ((l4*16) ^ swz01) + swz2;   // even kk
  const int rbO = l15*512 + ((l4*16) ^ swz01) - swz2;   // odd kk
  // epilogue base: byte = l15*512 + wav*128 + ((ie*32) ^ ((l15&6)<<4)) + ((l4*8) ^ ((l15&1)<<4))
  const int ebase = l15*512 + wav*128 + ((l4*8) ^ ((l15 & 1) << 4)) + ((l15 & 6) << 4);
  f32x4 acc[4][8];

  #pragma unroll
  for (int L = 0; L < 3; L++){
    const float* gb = (L == 0) ? gb1 : (L == 1) ? gb2 : gb3;

    // init accumulators with bias (feature e = wav*64 + ie*16 + l4*4 + j)
    #pragma unroll
    for (int ie = 0; ie < 4; ie++){
      f32x4 bbv = *(const f32x4*)(gb + wav*64 + ie*16 + l4*4);
      #pragma unroll
      for (int jp = 0; jp < 8; jp++) acc[ie][jp] = bbv;
    }

    #pragma unroll
    for (int kk = 0; kk < 8; kk++){
      short8 a0 = an0, a1 = an1, a2 = an2, a3 = an3;
      int pn = L*8 + kk + 1; if (pn > 23) pn = 23;
      LOADA(pn);                                     // next phase's A in flight
      const int rb = (kk & 1) ? rbO : rbE;
      short8 b[8];
      #pragma unroll
      for (int jp = 0; jp < 8; jp++)
        b[jp] = *(short8*)(lds + rb + jp*8192 + kk*64);
      __builtin_amdgcn_s_setprio(1);
      #pragma unroll
      for (int jp = 0; jp < 8; jp++){
        acc[0][jp] = __builtin_amdgcn_mfma_f32_16x16x32_bf16(a0, b[jp], acc[0][jp], 0, 0, 0);
        acc[1][jp] = __builtin_amdgcn_mfma_f32_16x16x32_bf16(a1, b[jp], acc[1][jp], 0, 0, 0);
        acc[2][jp] = __builtin_amdgcn_mfma_f32_16x16x32_bf16(a2, b[jp], acc[2][jp], 0, 0, 0);
        acc[3][jp] = __builtin_amdgcn_mfma_f32_16x16x32_bf16(a3, b[jp], acc[3][jp], 0, 0, 0);
      }
      __builtin_amdgcn_s_setprio(0);
    }

    if (L < 2){
      __syncthreads();                 // all waves done reading h_in
      #pragma unroll
      for (int ie = 0; ie < 4; ie++){
        int ea = ebase ^ (ie*32);
        #pragma unroll
        for (int jp = 0; jp < 8; jp++){
          uint2 pk;
          pk.x = cvtpk(fmaxf(acc[ie][jp][0], 0.f), fmaxf(acc[ie][jp][1], 0.f));
          pk.y = cvtpk(fmaxf(acc[ie][jp][2], 0.f), fmaxf(acc[ie][jp][3], 0.f));
          *(uint2*)(lds + ea + jp*8192) = pk;
        }
      }
      __syncthreads();                 // h_out visible to all waves
    } else {
      // layer 3: relu, mask tail pairs, sum over pairs -> atomic into rel
      #pragma unroll
      for (int ie = 0; ie < 4; ie++){
        int e0 = wav*64 + ie*16 + l4*4;
        f32x4 s = {0.f, 0.f, 0.f, 0.f};
        #pragma unroll
        for (int jp = 0; jp < 8; jp++){
          bool pv = fullvalid || (tbase + jp*16 + l15 < NPAIRS);
          #pragma unroll
          for (int j = 0; j < 4; j++){
            float hvv = fmaxf(acc[ie][jp][j], 0.f);
            s[j] += pv ? hvv : 0.f;
          }
        }
        #pragma unroll
        for (int st = 1; st < 16; st <<= 1){
          #pragma unroll
          for (int j = 0; j < 4; j++)
            s[j] += __shfl_xor(s[j], st);
        }
        if (l15 == 0){
          #pragma unroll
          for (int j = 0; j < 4; j++)
            atomicAdd(&rel[n*GT + e0 + j], s[j]);
        }
      }
    }
  }
#undef LOADA
}

// ---- f_phi: per-batch 256->256->256->28, f32 ----
__global__ void fphi(const float* __restrict__ rel,
                     const float* __restrict__ fW0, const float* __restrict__ fb0,
                     const float* __restrict__ fW1, const float* __restrict__ fb1,
                     const float* __restrict__ fW2, const float* __restrict__ fb2,
                     float* __restrict__ out){
  int n = blockIdx.x, t = threadIdx.x;
  __shared__ float h[256], y[256];
  h[t] = rel[n*GT + t];
  __syncthreads();
  float s = fb0[t];
  for (int k = 0; k < 256; k++) s += h[k] * fW0[k*GT + t];
  y[t] = fmaxf(s, 0.f);
  __syncthreads();
  s = fb1[t];
  for (int k = 0; k < 256; k++) s += y[k] * fW1[k*GT + t];
  __syncthreads();
  h[t] = fmaxf(s, 0.f);
  __syncthreads();
  if (t < 28){
    s = fb2[t];
    for (int k = 0; k < 256; k++) s += h[k] * fW2[k*28 + t];
    out[n*28 + t] = s;
  }
}

extern "C" void kernel_launch(void* const* d_in, const int* in_sizes, int n_in,
                              void* d_out, int out_size, void* d_ws, size_t ws_size,
                              hipStream_t stream){
  (void)in_sizes; (void)n_in; (void)out_size; (void)ws_size;
  const float* x   = (const float*)d_in[0];
  const float* q   = (const float*)d_in[1];
  const float* gW0 = (const float*)d_in[2];
  const float* gb0 = (const float*)d_in[3];
  const float* gW1 = (const float*)d_in[4];
  const float* gb1 = (const float*)d_in[5];
  const float* gW2 = (const float*)d_in[6];
  const float* gb2 = (const float*)d_in[7];
  const float* gW3 = (const float*)d_in[8];
  const float* gb3 = (const float*)d_in[9];
  const float* fW0 = (const float*)d_in[10];
  const float* fb0 = (const float*)d_in[11];
  const float* fW1 = (const float*)d_in[12];
  const float* fb1 = (const float*)d_in[13];
  const float* fW2 = (const float*)d_in[14];
  const float* fb2 = (const float*)d_in[15];

  char* ws = (char*)d_ws;
  unsigned short* WtP = (unsigned short*)(ws + WS_WT);
  unsigned short* u   = (unsigned short*)(ws + WS_U);
  unsigned short* v   = (unsigned short*)(ws + WS_V);
  float* rel = (float*)(ws + WS_REL);
  float* out = (float*)d_out;

  hipLaunchKernelGGL(prep_uv, dim3(NB*8), dim3(256), 0, stream, x, q, gW0, gb0, u, v);
  hipLaunchKernelGGL(prep_wt, dim3(768),  dim3(256), 0, stream, gW1, gW2, gW3, WtP, rel);
  hipLaunchKernelGGL(rn_main, dim3(NB*NT), dim3(256), 0, stream,
                     u, v, WtP, gb1, gb2, gb3, rel);
  hipLaunchKernelGGL(fphi, dim3(NB), dim3(256), 0, stream,
                     rel, fW0, fb0, fW1, fb1, fW2, fb2, out);
}